// Round 13
// baseline (132.599 us; speedup 1.0000x reference)
//
#include <hip/hip_runtime.h>
#include <hip/hip_bf16.h>
#include <math.h>

#define D 256
#define INV_TAU 20.0f
#define CAP 64
#define PBUF 256
#define K2 (20.0f * 1.442695040888963f)   // INV_TAU * log2(e)

typedef __attribute__((ext_vector_type(4))) float f32x4;
typedef __attribute__((ext_vector_type(8))) short bf16x8_t;

#define GLOAD16(gp, lp) \
    __builtin_amdgcn_global_load_lds((const __attribute__((address_space(1))) void*)(gp), \
                                     (__attribute__((address_space(3))) void*)(lp), 16, 0, 0)

__device__ __forceinline__ unsigned short f2bf(float f) {
    union { float f; unsigned u; } v; v.f = f;
    unsigned r = v.u + 0x7FFFu + ((v.u >> 16) & 1u);
    return (unsigned short)(r >> 16);
}

// Fused: L2-normalize every row of que/sen/sec into bf16. Wave per row.
__global__ void norm_all(const float* __restrict__ que, const float* __restrict__ sen,
                         const float* __restrict__ sec,
                         unsigned short* __restrict__ queb, unsigned short* __restrict__ senb,
                         unsigned short* __restrict__ secb, int Q, int N, int S) {
    int r = blockIdx.x * 4 + (threadIdx.x >> 6);
    int lane = threadIdx.x & 63;
    if (r >= Q + N + S) return;
    const float* src; unsigned short* dst; int row;
    if (r < Q) { src = que; dst = queb; row = r; }
    else if (r < Q + N) { src = sen; dst = senb; row = r - Q; }
    else { src = sec; dst = secb; row = r - Q - N; }
    const float4* p = (const float4*)(src + (size_t)row * D);
    float4 v = p[lane];
    float ss = v.x * v.x + v.y * v.y + v.z * v.z + v.w * v.w;
    #pragma unroll
    for (int m = 1; m < 64; m <<= 1) ss += __shfl_xor(ss, m);
    float rn = rsqrtf(ss);
    ushort4 o;
    o.x = f2bf(v.x * rn); o.y = f2bf(v.y * rn); o.z = f2bf(v.z * rn); o.w = f2bf(v.w * rn);
    *(ushort4*)(dst + (size_t)row * D + lane * 4) = o;
}

// Mega kernel, 512 threads (8 waves). Grid = 1024 QS blocks + 16 SQ tail blocks.
// QS: 256x256 tile, m201-style phased schedule. BK=64 split in 2 K-halves;
// LDS [2 dbuf][2 kh][256x32] bf16 per matrix (128 KB total, 1 block/CU).
// 4 phases per K-tile: {ds_read frags | stage 1 half-tile | barrier |
// setprio(1) 16 MFMA setprio(0) | barrier}; counted vmcnt(4) twice per K-tile
// (never 0 mid-loop): half-tile = 4 loads/wave, distance-1-tile prefetch into
// the opposite dbuf. Read/source chunk swizzle ch ^= (row>>1)&3 (2-way-free).
__global__ __launch_bounds__(512, 2)
void qs_sq(const unsigned short* __restrict__ queb, const unsigned short* __restrict__ senb,
           const unsigned short* __restrict__ secb,
           const int* __restrict__ pidq, const int* __restrict__ pidn,
           const int* __restrict__ sidx, int Q, int N,
           float* __restrict__ partial, int* __restrict__ cnt, float* __restrict__ pos_s,
           float* __restrict__ sq_all, float* __restrict__ sq_pos, int* __restrict__ sq_m,
           float* __restrict__ simq) {
    __shared__ unsigned short As[2][2][8192];   // [dbuf][kh][row*32 + swz-chunk*8]
    __shared__ unsigned short Bs[2][2][8192];
    __shared__ int pqs[256];
    __shared__ int pns[256];

    const int tid = threadIdx.x;
    const int lane = tid & 63;
    const int cl = lane & 15;
    const int g = lane >> 4;
    const int wid = tid >> 6;
    const int bid = blockIdx.x;
    const int nsqb = Q >> 8;                  // 16 SQ blocks, at grid tail
    const int nqs = gridDim.x - nsqb;         // 1024 QS blocks

    if (bid >= nqs) {
        // ---------------- SQ path: 64 sections x 256 questions ----------------
        const int q0 = (bid - nqs) * 256;
        const int qw = q0 + wid * 32;
        f32x4 acc[4][2];
        #pragma unroll
        for (int si = 0; si < 4; ++si)
            #pragma unroll
            for (int qi = 0; qi < 2; ++qi)
                acc[si][qi] = (f32x4){0.f, 0.f, 0.f, 0.f};
        const unsigned short* abase = secb + (size_t)cl * D + g * 8;
        const unsigned short* bbase = queb + (size_t)(qw + cl) * D + g * 8;
        #pragma unroll
        for (int kk = 0; kk < 8; ++kk) {
            const int k0 = kk * 32;
            bf16x8_t af[4], bq[2];
            #pragma unroll
            for (int si = 0; si < 4; ++si)
                af[si] = *(const bf16x8_t*)(abase + si * 16 * D + k0);
            #pragma unroll
            for (int qi = 0; qi < 2; ++qi)
                bq[qi] = *(const bf16x8_t*)(bbase + qi * 16 * D + k0);
            #pragma unroll
            for (int si = 0; si < 4; ++si)
                #pragma unroll
                for (int qi = 0; qi < 2; ++qi)
                    acc[si][qi] = __builtin_amdgcn_mfma_f32_16x16x32_bf16(af[si], bq[qi], acc[si][qi], 0, 0, 0);
        }
        int sidxv[2];
        sidxv[0] = sidx[qw + cl];
        sidxv[1] = sidx[qw + 16 + cl];
        #pragma unroll
        for (int si = 0; si < 4; ++si) {
            float pa[4] = {0.f, 0.f, 0.f, 0.f};
            #pragma unroll
            for (int qi = 0; qi < 2; ++qi) {
                #pragma unroll
                for (int j = 0; j < 4; ++j) {
                    int srow = si * 16 + g * 4 + j;
                    float sv = acc[si][qi][j] * INV_TAU;
                    float e = __expf(sv);
                    pa[j] += e;
                    if (sidxv[qi] == srow) {
                        int q = qw + qi * 16 + cl;
                        simq[q] = sv;
                        atomicAdd(&sq_pos[srow], e);
                        atomicAdd(&sq_m[srow], 1);
                    }
                }
            }
            #pragma unroll
            for (int j = 0; j < 4; ++j) {
                float a = pa[j];
                #pragma unroll
                for (int msk = 1; msk < 16; msk <<= 1) a += __shfl_xor(a, msk);
                if (cl == 0) atomicAdd(&sq_all[si * 16 + g * 4 + j], a);
            }
        }
        return;
    }

    // ---------------- QS path: one 256x256 tile ----------------
    const int nnt = N >> 8;            // 64 n-tiles
    const int qt = bid / nnt;
    const int nt = bid % nnt;
    const int wrow = wid >> 2;         // 0..1
    const int wcol = wid & 3;          // 0..3
    const int q0 = qt * 256;
    const int n0 = nt * 256;

    if (tid < 256) pqs[tid] = pidq[q0 + tid];
    else           pns[tid - 256] = pidn[n0 + tid - 256];
    __syncthreads();   // pid visible + vmcnt drained before counted waits

    // Staging geometry: half-tile = one matrix, one kh: 256 rows x 32 el = 16 KB
    // = 2 gload insts/thread. Thread covers chunk c = tid (rows 0..127) and
    // c = tid+512 (rows 128..255); ch = tid&3; source chunk col within row =
    // kh*4 + (ch ^ ((row>>1)&3)); LDS dest linear in c within [dbuf][kh] region.
    const int r0 = tid >> 2;
    const int ch = tid & 3;
    const int sw = (r0 >> 1) & 3;                  // same for r0 and r0+128
    const int xo = ((ch ^ sw) << 3);
    const unsigned short* qa0 = queb + (size_t)(q0 + r0) * D + xo;
    const unsigned short* qa1 = queb + (size_t)(q0 + r0 + 128) * D + xo;
    const unsigned short* sb0 = senb + (size_t)(n0 + r0) * D + xo;
    const unsigned short* sb1 = senb + (size_t)(n0 + r0 + 128) * D + xo;
    const int ldw0 = wid * 512;          // element base, inst 0 (wave-uniform)
    const int ldw1 = 4096 + wid * 512;   // inst 1

#define STAGE_A(buf, kh, kt) do { \
    GLOAD16(qa0 + (kt) * 64 + (kh) * 32, &As[buf][kh][ldw0]); \
    GLOAD16(qa1 + (kt) * 64 + (kh) * 32, &As[buf][kh][ldw1]); \
} while (0)
#define STAGE_B(buf, kh, kt) do { \
    GLOAD16(sb0 + (kt) * 64 + (kh) * 32, &Bs[buf][kh][ldw0]); \
    GLOAD16(sb1 + (kt) * 64 + (kh) * 32, &Bs[buf][kh][ldw1]); \
} while (0)

    f32x4 acc[8][4];
    #pragma unroll
    for (int m = 0; m < 8; ++m)
        #pragma unroll
        for (int n = 0; n < 4; ++n)
            acc[m][n] = (f32x4){0.f, 0.f, 0.f, 0.f};

    // Fragment read offsets within a [256][32] kh region: row*32 + (g^swz)*8,
    // swz = (row>>1)&3 = (cl>>1)&3 (fragment row bases are multiples of 16).
    const int fsw = ((g ^ ((cl >> 1) & 3)) << 3);
    int offA[8], offB[4];
    #pragma unroll
    for (int m = 0; m < 8; ++m) offA[m] = (wrow * 128 + m * 16 + cl) * 32 + fsw;
    #pragma unroll
    for (int n = 0; n < 4; ++n) offB[n] = (wcol * 64 + n * 16 + cl) * 32 + fsw;

#define PHASE_MFMA(np, AA, B0, B1) do { \
    __builtin_amdgcn_s_setprio(1); \
    _Pragma("unroll") \
    for (int m_ = 0; m_ < 8; ++m_) { \
        acc[m_][(np) * 2]     = __builtin_amdgcn_mfma_f32_16x16x32_bf16(AA[m_], B0, acc[m_][(np) * 2], 0, 0, 0); \
        acc[m_][(np) * 2 + 1] = __builtin_amdgcn_mfma_f32_16x16x32_bf16(AA[m_], B1, acc[m_][(np) * 2 + 1], 0, 0, 0); \
    } \
    __builtin_amdgcn_s_setprio(0); \
} while (0)

    // Prologue: stage tile 0 (order Akh0, Bkh0, Akh1, Bkh1 = 8 loads/thread),
    // wait for the first K-half (oldest 4), rendezvous.
    STAGE_A(0, 0, 0); STAGE_B(0, 0, 0);
    STAGE_A(0, 1, 0); STAGE_B(0, 1, 0);
    asm volatile("s_waitcnt vmcnt(4)" ::: "memory");
    __syncthreads();

    #pragma unroll
    for (int t = 0; t < 4; ++t) {
        const int cb = t & 1, nb = cb ^ 1;
        bf16x8_t a0[8], b0, b1;
        // ---- phase 0: kk=0, n-pair 0
        #pragma unroll
        for (int m = 0; m < 8; ++m) a0[m] = *(const bf16x8_t*)&As[cb][0][offA[m]];
        b0 = *(const bf16x8_t*)&Bs[cb][0][offB[0]];
        b1 = *(const bf16x8_t*)&Bs[cb][0][offB[1]];
        if (t < 3) STAGE_A(nb, 0, t + 1);
        __builtin_amdgcn_s_barrier();
        PHASE_MFMA(0, a0, b0, b1);
        __builtin_amdgcn_s_barrier();
        // ---- phase 1: kk=0, n-pair 1  (end: guard kh1 of tile t)
        b0 = *(const bf16x8_t*)&Bs[cb][0][offB[2]];
        b1 = *(const bf16x8_t*)&Bs[cb][0][offB[3]];
        if (t < 3) STAGE_B(nb, 0, t + 1);
        if (t < 3) asm volatile("s_waitcnt vmcnt(4)" ::: "memory");
        else       asm volatile("s_waitcnt vmcnt(0)" ::: "memory");
        __builtin_amdgcn_s_barrier();
        PHASE_MFMA(1, a0, b0, b1);
        __builtin_amdgcn_s_barrier();
        // ---- phase 2: kk=1, n-pair 0
        #pragma unroll
        for (int m = 0; m < 8; ++m) a0[m] = *(const bf16x8_t*)&As[cb][1][offA[m]];
        b0 = *(const bf16x8_t*)&Bs[cb][1][offB[0]];
        b1 = *(const bf16x8_t*)&Bs[cb][1][offB[1]];
        if (t < 3) STAGE_A(nb, 1, t + 1);
        __builtin_amdgcn_s_barrier();
        PHASE_MFMA(0, a0, b0, b1);
        __builtin_amdgcn_s_barrier();
        // ---- phase 3: kk=1, n-pair 1  (end: guard kh0 of tile t+1)
        b0 = *(const bf16x8_t*)&Bs[cb][1][offB[2]];
        b1 = *(const bf16x8_t*)&Bs[cb][1][offB[3]];
        if (t < 3) {
            STAGE_B(nb, 1, t + 1);
            asm volatile("s_waitcnt vmcnt(4)" ::: "memory");
        }
        __builtin_amdgcn_s_barrier();
        PHASE_MFMA(1, a0, b0, b1);
        __builtin_amdgcn_s_barrier();
    }
#undef STAGE_A
#undef STAGE_B
#undef PHASE_MFMA

    // Epilogue: LDS tiles are dead — alias scratch onto As.
    __syncthreads();
    float (*sums)[256] = (float(*)[256])&As[0][0][0];          // 4 KB
    int*   lq   = (int*)((char*)&As[0][0][0] + 4096);          // PBUF ints
    float* lsv  = (float*)((char*)&As[0][0][0] + 4096 + PBUF * 4);
    int*   lcnt = (int*)((char*)&As[0][0][0] + 4096 + PBUF * 8);
    if (tid == 0) *lcnt = 0;
    __syncthreads();

    float se[32];
    #pragma unroll
    for (int i = 0; i < 32; ++i) se[i] = 0.f;
    #pragma unroll
    for (int m = 0; m < 8; ++m) {
        int pqr[4];
        #pragma unroll
        for (int j = 0; j < 4; ++j) pqr[j] = pqs[wrow * 128 + m * 16 + g * 4 + j];
        #pragma unroll
        for (int n = 0; n < 4; ++n) {
            const int pcol = pns[wcol * 64 + n * 16 + cl];
            #pragma unroll
            for (int j = 0; j < 4; ++j) {
                float e = __builtin_amdgcn_exp2f(acc[m][n][j] * K2);
                se[m * 4 + j] += e;
                if (pqr[j] == pcol) {
                    int li = atomicAdd(lcnt, 1);
                    if (li < PBUF) {
                        lq[li] = q0 + wrow * 128 + m * 16 + g * 4 + j;
                        lsv[li] = acc[m][n][j] * INV_TAU;
                    }
                }
            }
        }
    }
    #pragma unroll
    for (int i = 0; i < 32; ++i) {
        float a = se[i];
        #pragma unroll
        for (int msk = 1; msk < 16; msk <<= 1) a += __shfl_xor(a, msk);
        if (cl == 0)
            sums[wcol][wrow * 128 + (i >> 2) * 16 + g * 4 + (i & 3)] = a;
    }
    __syncthreads();
    if (tid < 256)
        partial[(size_t)nt * Q + q0 + tid] =
            sums[0][tid] + sums[1][tid] + sums[2][tid] + sums[3][tid];
    int nc = *lcnt < PBUF ? *lcnt : PBUF;
    for (int i = tid; i < nc; i += 512) {
        int q = lq[i];
        int idx = atomicAdd(&cnt[q], 1);
        if (idx < CAP) pos_s[(size_t)q * CAP + idx] = lsv[i];
    }
}

// Finish: wave per question. Reduces row partials, computes g + QS terms + SQ term.
__global__ __launch_bounds__(256)
void finish(const float* __restrict__ partial, int NSLICE,
            const int* __restrict__ cnt, const float* __restrict__ pos_s,
            const int* __restrict__ sidx, const float* __restrict__ simq,
            const float* __restrict__ sq_all, const float* __restrict__ sq_pos,
            const int* __restrict__ sq_m,
            const int* __restrict__ npp, int Qn, int Ntot,
            float* __restrict__ bpart) {
    __shared__ float fred[4][4];
    const int tid = threadIdx.x, lane = tid & 63, wid = tid >> 6;
    const int q = blockIdx.x * 4 + wid;

    float Sa = 0.f;
    for (int nb = lane; nb < NSLICE; nb += 64) Sa += partial[(size_t)nb * Qn + q];
    #pragma unroll
    for (int m = 1; m < 64; m <<= 1) Sa += __shfl_xor(Sa, m);

    int M = cnt[q];
    int mc = M < CAP ? M : CAP;
    float s = 0.f, e = 0.f;
    if (lane < mc) { s = pos_s[(size_t)q * CAP + lane]; e = __expf(s); }
    float Sp = e;
    #pragma unroll
    for (int m = 1; m < 64; m <<= 1) Sp += __shfl_xor(Sp, m);

    int Nn = Ntot - M;
    int P = npp[0];
    float eta_p = 1.0f / (float)(P > 1 ? P : 1);
    float eta_m = 1.0f - eta_p;
    float Mf = (float)(M > 1 ? M : 1);
    float Nnf = (float)(Nn > 1 ? Nn : 1);
    float gg = fmaxf(((Sa - Sp) / Nnf - eta_p * Sp / Mf) / eta_m, __expf(-INV_TAU));
    float c = (float)Nn * gg;

    float contrib = (lane < mc) ? (s - __logf(e + c)) : 0.f;
    #pragma unroll
    for (int m = 1; m < 64; m <<= 1) contrib += __shfl_xor(contrib, m);

    if (lane == 0) {
        float qs_num = 0.f, qs_cnt = 0.f, sq_num = 0.f, sq_cnt = 0.f;
        if (M > 0 && Nn > 0) { qs_num = contrib; qs_cnt = (float)M; }
        int sct = sidx[q];
        int Mq = sq_m[sct];
        if (Mq > 0 && (Qn - Mq) > 0) {
            float sv = simq[q];
            float sumneg = sq_all[sct] - sq_pos[sct];
            sq_num = sv - __logf(__expf(sv) + sumneg);
            sq_cnt = 1.f;
        }
        fred[wid][0] = qs_num; fred[wid][1] = qs_cnt;
        fred[wid][2] = sq_num; fred[wid][3] = sq_cnt;
    }
    __syncthreads();
    if (tid < 4) {
        float v = fred[0][tid] + fred[1][tid] + fred[2][tid] + fred[3][tid];
        bpart[(size_t)blockIdx.x * 4 + tid] = v;
    }
}

__global__ void combine2(const float* __restrict__ bpart, int nblk, float* __restrict__ out) {
    __shared__ float r2[4][4];
    const int tid = threadIdx.x, lane = tid & 63, wid = tid >> 6;
    float v[4] = {0.f, 0.f, 0.f, 0.f};
    for (int i = tid; i < nblk; i += 256) {
        #pragma unroll
        for (int c2 = 0; c2 < 4; ++c2) v[c2] += bpart[(size_t)i * 4 + c2];
    }
    #pragma unroll
    for (int m = 1; m < 64; m <<= 1)
        #pragma unroll
        for (int c2 = 0; c2 < 4; ++c2) v[c2] += __shfl_xor(v[c2], m);
    if (lane == 0) {
        #pragma unroll
        for (int c2 = 0; c2 < 4; ++c2) r2[wid][c2] = v[c2];
    }
    __syncthreads();
    if (tid == 0) {
        float qs_num = r2[0][0] + r2[1][0] + r2[2][0] + r2[3][0];
        float qs_cnt = r2[0][1] + r2[1][1] + r2[2][1] + r2[3][1];
        float sq_num = r2[0][2] + r2[1][2] + r2[2][2] + r2[3][2];
        float sq_cnt = r2[0][3] + r2[1][3] + r2[2][3] + r2[3][3];
        float qs = qs_cnt > 0.f ? -qs_num / qs_cnt : 0.f;
        float sq = sq_cnt > 0.f ? -sq_num / sq_cnt : 0.f;
        out[0] = qs + sq;
    }
}

extern "C" void kernel_launch(void* const* d_in, const int* in_sizes, int n_in,
                              void* d_out, int out_size, void* d_ws, size_t ws_size,
                              hipStream_t stream) {
    const float* sec = (const float*)d_in[1];
    const float* que = (const float*)d_in[2];
    const float* sen = (const float*)d_in[3];
    const int* pidq = (const int*)d_in[4];
    const int* sidx = (const int*)d_in[5];
    const int* pidn = (const int*)d_in[6];
    const int* npp = (const int*)d_in[7];
    const int S = in_sizes[1] / D;
    const int Q = in_sizes[2] / D;
    const int N = in_sizes[3] / D;
    const int NSLICE = N / 256;   // 64
    const int FBLK = Q / 4;

    char* p = (char*)d_ws;
    unsigned short* queb = (unsigned short*)p; p += (size_t)Q * D * 2;
    unsigned short* senb = (unsigned short*)p; p += (size_t)N * D * 2;
    unsigned short* secb = (unsigned short*)p; p += (size_t)S * D * 2;
    float* simq = (float*)p; p += (size_t)Q * 4;
    float* pos_s = (float*)p; p += (size_t)Q * CAP * 4;
    float* partial = (float*)p; p += (size_t)NSLICE * Q * 4;
    float* bpart = (float*)p; p += (size_t)FBLK * 4 * 4;
    char* z0 = p;
    int* cnt = (int*)p; p += (size_t)Q * 4;
    float* sq_all = (float*)p; p += (size_t)S * 4;
    float* sq_pos = (float*)p; p += (size_t)S * 4;
    int* sq_m = (int*)p; p += (size_t)S * 4;
    size_t zbytes = (size_t)(p - z0);

    hipMemsetAsync(z0, 0, zbytes, stream);
    norm_all<<<(Q + N + S + 3) / 4, 256, 0, stream>>>(que, sen, sec, queb, senb, secb, Q, N, S);
    // (Q/256)*(N/256) = 1024 QS blocks (exactly 4 rounds at 1 block/CU) + 16 SQ tail.
    qs_sq<<<(Q / 256) * (N / 256) + Q / 256, 512, 0, stream>>>(queb, senb, secb, pidq, pidn,
                                                               sidx, Q, N, partial, cnt, pos_s,
                                                               sq_all, sq_pos, sq_m, simq);
    finish<<<FBLK, 256, 0, stream>>>(partial, NSLICE, cnt, pos_s, sidx, simq,
                                     sq_all, sq_pos, sq_m, npp, Q, N, bpart);
    combine2<<<1, 256, 0, stream>>>(bpart, FBLK, (float*)d_out);
}

// Round 14
// 108.584 us; speedup vs baseline: 1.2212x; 1.2212x over previous
//
#include <hip/hip_runtime.h>
#include <hip/hip_bf16.h>
#include <math.h>

#define D 256
#define INV_TAU 20.0f
#define CAP 64
#define WPB 64     // per-wave capture buffer
#define K2 (20.0f * 1.442695040888963f)   // INV_TAU * log2(e)

typedef __attribute__((ext_vector_type(4))) float f32x4;
typedef __attribute__((ext_vector_type(8))) short bf16x8_t;

#define GLOAD16(gp, lp) \
    __builtin_amdgcn_global_load_lds((const __attribute__((address_space(1))) void*)(gp), \
                                     (__attribute__((address_space(3))) void*)(lp), 16, 0, 0)

__device__ __forceinline__ unsigned short f2bf(float f) {
    union { float f; unsigned u; } v; v.f = f;
    unsigned r = v.u + 0x7FFFu + ((v.u >> 16) & 1u);
    return (unsigned short)(r >> 16);
}

// Fused: L2-normalize every row of que/sen/sec into bf16. Wave per row.
__global__ void norm_all(const float* __restrict__ que, const float* __restrict__ sen,
                         const float* __restrict__ sec,
                         unsigned short* __restrict__ queb, unsigned short* __restrict__ senb,
                         unsigned short* __restrict__ secb, int Q, int N, int S) {
    int r = blockIdx.x * 4 + (threadIdx.x >> 6);
    int lane = threadIdx.x & 63;
    if (r >= Q + N + S) return;
    const float* src; unsigned short* dst; int row;
    if (r < Q) { src = que; dst = queb; row = r; }
    else if (r < Q + N) { src = sen; dst = senb; row = r - Q; }
    else { src = sec; dst = secb; row = r - Q - N; }
    const float4* p = (const float4*)(src + (size_t)row * D);
    float4 v = p[lane];
    float ss = v.x * v.x + v.y * v.y + v.z * v.z + v.w * v.w;
    #pragma unroll
    for (int m = 1; m < 64; m <<= 1) ss += __shfl_xor(ss, m);
    float rn = rsqrtf(ss);
    ushort4 o;
    o.x = f2bf(v.x * rn); o.y = f2bf(v.y * rn); o.z = f2bf(v.z * rn); o.w = f2bf(v.w * rn);
    *(ushort4*)(dst + (size_t)row * D + lane * 4) = o;
}

// Mega kernel, 256 threads = 4 INDEPENDENT waves (no __syncthreads in QS path).
// Each wave owns a 64x64 tile: private 8KB LDS buffer, single-buffered BK=32,
// per-wave pipeline: vmcnt(0) -> ds_read frags -> lgkmcnt(0)+sched_barrier ->
// STAGE(next, same buffer) -> 16 MFMA. Free-running waves hide each other's
// stalls (m114 overlap without barrier lockstep). Swizzle ch ^= (row>>1)&3
// (R6-verified 2-way-free) on source + read, linear LDS dest (rule #21).
__global__ __launch_bounds__(256, 4)
void qs_sq(const unsigned short* __restrict__ queb, const unsigned short* __restrict__ senb,
           const unsigned short* __restrict__ secb,
           const int* __restrict__ pidq, const int* __restrict__ pidn,
           const int* __restrict__ sidx, int Q,
           float* __restrict__ partial, int* __restrict__ cnt, float* __restrict__ pos_s,
           float* __restrict__ sq_all, float* __restrict__ sq_pos, int* __restrict__ sq_m,
           float* __restrict__ simq) {
    __shared__ unsigned short As[4][2048];   // [wave][64 rows x 32 el]
    __shared__ unsigned short Bs[4][2048];
    __shared__ int lcnt[4];
    __shared__ int lq[4][WPB];
    __shared__ float lsv[4][WPB];

    const int tid = threadIdx.x;
    const int lane = tid & 63;
    const int cl = lane & 15;
    const int g = lane >> 4;
    const int wid = tid >> 6;
    const int bid = blockIdx.x;
    const int nsq = Q >> 7;   // 32 SQ blocks

    if (bid < nsq) {
        // ---------------- SQ path: 64 sections x 128 questions ----------------
        const int q0 = bid * 128;
        const int qw = q0 + wid * 32;
        f32x4 acc[4][2];
        #pragma unroll
        for (int si = 0; si < 4; ++si)
            #pragma unroll
            for (int qi = 0; qi < 2; ++qi)
                acc[si][qi] = (f32x4){0.f, 0.f, 0.f, 0.f};
        const unsigned short* abase = secb + (size_t)cl * D + g * 8;
        const unsigned short* bbase = queb + (size_t)(qw + cl) * D + g * 8;
        #pragma unroll
        for (int kk = 0; kk < 8; ++kk) {
            const int k0 = kk * 32;
            bf16x8_t af[4], bq[2];
            #pragma unroll
            for (int si = 0; si < 4; ++si)
                af[si] = *(const bf16x8_t*)(abase + si * 16 * D + k0);
            #pragma unroll
            for (int qi = 0; qi < 2; ++qi)
                bq[qi] = *(const bf16x8_t*)(bbase + qi * 16 * D + k0);
            #pragma unroll
            for (int si = 0; si < 4; ++si)
                #pragma unroll
                for (int qi = 0; qi < 2; ++qi)
                    acc[si][qi] = __builtin_amdgcn_mfma_f32_16x16x32_bf16(af[si], bq[qi], acc[si][qi], 0, 0, 0);
        }
        int sidxv[2];
        sidxv[0] = sidx[qw + cl];
        sidxv[1] = sidx[qw + 16 + cl];
        #pragma unroll
        for (int si = 0; si < 4; ++si) {
            float pa[4] = {0.f, 0.f, 0.f, 0.f};
            #pragma unroll
            for (int qi = 0; qi < 2; ++qi) {
                #pragma unroll
                for (int j = 0; j < 4; ++j) {
                    int srow = si * 16 + g * 4 + j;
                    float sv = acc[si][qi][j] * INV_TAU;
                    float e = __expf(sv);
                    pa[j] += e;
                    if (sidxv[qi] == srow) {
                        int q = qw + qi * 16 + cl;
                        simq[q] = sv;
                        atomicAdd(&sq_pos[srow], e);
                        atomicAdd(&sq_m[srow], 1);
                    }
                }
            }
            #pragma unroll
            for (int j = 0; j < 4; ++j) {
                float a = pa[j];
                #pragma unroll
                for (int msk = 1; msk < 16; msk <<= 1) a += __shfl_xor(a, msk);
                if (cl == 0) atomicAdd(&sq_all[si * 16 + g * 4 + j], a);
            }
        }
        return;
    }

    // ---------------- QS path: per-wave independent 64x64 tiles ----------------
    // Block = 128x128 macro-tile (L2 locality), wave (wr,wc) of 2x2 covers 64x64.
    const int qbid = bid - nsq;
    const int mq = qbid & 31;          // 32 q-macros (fastest: share n-range in L2)
    const int mn = qbid >> 5;          // 128 n-macros
    const int q0w = mq * 128 + (wid >> 1) * 64;
    const int ntg = mn * 2 + (wid & 1);     // global 64-wide n-tile id, 0..255
    const int n0w = ntg * 64;

    if (lane == 0) lcnt[wid] = 0;

    // Staging: 64 rows x 32 el = 256 chunks per matrix; lane covers cid = j*64+lane
    // (j=0..3): row = j*16 + (lane>>2), ch = lane&3. Source chunk col =
    // ch ^ ((row>>1)&3); (row>>1)&3 = (lane>>3)&3 (j*16 preserves mod-4 of row>>1).
    const int srow = lane >> 2;
    const int scol = ((lane & 3) ^ ((lane >> 3) & 3)) << 3;
    const unsigned short* qa = queb + (size_t)(q0w + srow) * D + scol;
    const unsigned short* sb = senb + (size_t)(n0w + srow) * D + scol;

#define STAGE(k0) do { \
    _Pragma("unroll") \
    for (int j_ = 0; j_ < 4; ++j_) { \
        GLOAD16(qa + (k0) + j_ * 16 * D, &As[wid][j_ * 512]); \
        GLOAD16(sb + (k0) + j_ * 16 * D, &Bs[wid][j_ * 512]); \
    } } while (0)

    f32x4 acc[4][4];
    #pragma unroll
    for (int m = 0; m < 4; ++m)
        #pragma unroll
        for (int n = 0; n < 4; ++n)
            acc[m][n] = (f32x4){0.f, 0.f, 0.f, 0.f};

    // Fragment read offsets: want chunk (r, g), stored col = g ^ ((r>>1)&3);
    // (r>>1)&3 == (cl>>1)&3 (fragment row bases are multiples of 16).
    const int fsw = (g ^ ((cl >> 1) & 3)) << 3;
    int offA[4], offB[4];
    #pragma unroll
    for (int m = 0; m < 4; ++m) offA[m] = (m * 16 + cl) * 32 + fsw;
    #pragma unroll
    for (int n = 0; n < 4; ++n) offB[n] = (n * 16 + cl) * 32 + fsw;

    STAGE(0);
    #pragma unroll
    for (int ks = 0; ks < 8; ++ks) {
        asm volatile("s_waitcnt vmcnt(0)" ::: "memory");   // own loads landed
        bf16x8_t af[4], bg[4];
        #pragma unroll
        for (int m = 0; m < 4; ++m) af[m] = *(const bf16x8_t*)&As[wid][offA[m]];
        #pragma unroll
        for (int n = 0; n < 4; ++n) bg[n] = *(const bf16x8_t*)&Bs[wid][offB[n]];
        asm volatile("s_waitcnt lgkmcnt(0)" ::: "memory"); // frags in regs
        __builtin_amdgcn_sched_barrier(0);                 // rule #18 fence
        if (ks < 7) STAGE((ks + 1) * 32);                  // overwrite is now safe
        #pragma unroll
        for (int m = 0; m < 4; ++m)
            #pragma unroll
            for (int n = 0; n < 4; ++n)
                acc[m][n] = __builtin_amdgcn_mfma_f32_16x16x32_bf16(af[m], bg[n], acc[m][n], 0, 0, 0);
    }
#undef STAGE

    // Per-wave epilogue (no block sync): pids from global (L1/L2-cached).
    int pcol[4];
    #pragma unroll
    for (int n = 0; n < 4; ++n) pcol[n] = pidn[n0w + n * 16 + cl];
    #pragma unroll
    for (int m = 0; m < 4; ++m) {
        float se[4] = {0.f, 0.f, 0.f, 0.f};
        int pqr[4];
        #pragma unroll
        for (int j = 0; j < 4; ++j) pqr[j] = pidq[q0w + m * 16 + g * 4 + j];
        #pragma unroll
        for (int n = 0; n < 4; ++n) {
            #pragma unroll
            for (int j = 0; j < 4; ++j) {
                float e = __builtin_amdgcn_exp2f(acc[m][n][j] * K2);
                se[j] += e;
                if (pqr[j] == pcol[n]) {
                    int li = atomicAdd(&lcnt[wid], 1);
                    if (li < WPB) {
                        lq[wid][li] = q0w + m * 16 + g * 4 + j;
                        lsv[wid][li] = acc[m][n][j] * INV_TAU;
                    }
                }
            }
        }
        #pragma unroll
        for (int j = 0; j < 4; ++j) {
            float a = se[j];
            #pragma unroll
            for (int msk = 1; msk < 16; msk <<= 1) a += __shfl_xor(a, msk);
            if (cl == 0)
                partial[(size_t)ntg * Q + q0w + m * 16 + g * 4 + j] = a;
        }
    }
    asm volatile("s_waitcnt lgkmcnt(0)" ::: "memory");   // capture atomics done
    int nc = lcnt[wid] < WPB ? lcnt[wid] : WPB;
    for (int i = lane; i < nc; i += 64) {
        int q = lq[wid][i];
        int idx = atomicAdd(&cnt[q], 1);
        if (idx < CAP) pos_s[(size_t)q * CAP + idx] = lsv[wid][i];
    }
}

// Finish: wave per question. Reduces row partials, computes g + QS terms + SQ term.
__global__ __launch_bounds__(256)
void finish(const float* __restrict__ partial, int NSLICE,
            const int* __restrict__ cnt, const float* __restrict__ pos_s,
            const int* __restrict__ sidx, const float* __restrict__ simq,
            const float* __restrict__ sq_all, const float* __restrict__ sq_pos,
            const int* __restrict__ sq_m,
            const int* __restrict__ npp, int Qn, int Ntot,
            float* __restrict__ bpart) {
    __shared__ float fred[4][4];
    const int tid = threadIdx.x, lane = tid & 63, wid = tid >> 6;
    const int q = blockIdx.x * 4 + wid;

    float Sa = 0.f;
    for (int nb = lane; nb < NSLICE; nb += 64) Sa += partial[(size_t)nb * Qn + q];
    #pragma unroll
    for (int m = 1; m < 64; m <<= 1) Sa += __shfl_xor(Sa, m);

    int M = cnt[q];
    int mc = M < CAP ? M : CAP;
    float s = 0.f, e = 0.f;
    if (lane < mc) { s = pos_s[(size_t)q * CAP + lane]; e = __expf(s); }
    float Sp = e;
    #pragma unroll
    for (int m = 1; m < 64; m <<= 1) Sp += __shfl_xor(Sp, m);

    int Nn = Ntot - M;
    int P = npp[0];
    float eta_p = 1.0f / (float)(P > 1 ? P : 1);
    float eta_m = 1.0f - eta_p;
    float Mf = (float)(M > 1 ? M : 1);
    float Nnf = (float)(Nn > 1 ? Nn : 1);
    float gg = fmaxf(((Sa - Sp) / Nnf - eta_p * Sp / Mf) / eta_m, __expf(-INV_TAU));
    float c = (float)Nn * gg;

    float contrib = (lane < mc) ? (s - __logf(e + c)) : 0.f;
    #pragma unroll
    for (int m = 1; m < 64; m <<= 1) contrib += __shfl_xor(contrib, m);

    if (lane == 0) {
        float qs_num = 0.f, qs_cnt = 0.f, sq_num = 0.f, sq_cnt = 0.f;
        if (M > 0 && Nn > 0) { qs_num = contrib; qs_cnt = (float)M; }
        int sct = sidx[q];
        int Mq = sq_m[sct];
        if (Mq > 0 && (Qn - Mq) > 0) {
            float sv = simq[q];
            float sumneg = sq_all[sct] - sq_pos[sct];
            sq_num = sv - __logf(__expf(sv) + sumneg);
            sq_cnt = 1.f;
        }
        fred[wid][0] = qs_num; fred[wid][1] = qs_cnt;
        fred[wid][2] = sq_num; fred[wid][3] = sq_cnt;
    }
    __syncthreads();
    if (tid < 4) {
        float v = fred[0][tid] + fred[1][tid] + fred[2][tid] + fred[3][tid];
        bpart[(size_t)blockIdx.x * 4 + tid] = v;
    }
}

__global__ void combine2(const float* __restrict__ bpart, int nblk, float* __restrict__ out) {
    __shared__ float r2[4][4];
    const int tid = threadIdx.x, lane = tid & 63, wid = tid >> 6;
    float v[4] = {0.f, 0.f, 0.f, 0.f};
    for (int i = tid; i < nblk; i += 256) {
        #pragma unroll
        for (int c2 = 0; c2 < 4; ++c2) v[c2] += bpart[(size_t)i * 4 + c2];
    }
    #pragma unroll
    for (int m = 1; m < 64; m <<= 1)
        #pragma unroll
        for (int c2 = 0; c2 < 4; ++c2) v[c2] += __shfl_xor(v[c2], m);
    if (lane == 0) {
        #pragma unroll
        for (int c2 = 0; c2 < 4; ++c2) r2[wid][c2] = v[c2];
    }
    __syncthreads();
    if (tid == 0) {
        float qs_num = r2[0][0] + r2[1][0] + r2[2][0] + r2[3][0];
        float qs_cnt = r2[0][1] + r2[1][1] + r2[2][1] + r2[3][1];
        float sq_num = r2[0][2] + r2[1][2] + r2[2][2] + r2[3][2];
        float sq_cnt = r2[0][3] + r2[1][3] + r2[2][3] + r2[3][3];
        float qs = qs_cnt > 0.f ? -qs_num / qs_cnt : 0.f;
        float sq = sq_cnt > 0.f ? -sq_num / sq_cnt : 0.f;
        out[0] = qs + sq;
    }
}

extern "C" void kernel_launch(void* const* d_in, const int* in_sizes, int n_in,
                              void* d_out, int out_size, void* d_ws, size_t ws_size,
                              hipStream_t stream) {
    const float* sec = (const float*)d_in[1];
    const float* que = (const float*)d_in[2];
    const float* sen = (const float*)d_in[3];
    const int* pidq = (const int*)d_in[4];
    const int* sidx = (const int*)d_in[5];
    const int* pidn = (const int*)d_in[6];
    const int* npp = (const int*)d_in[7];
    const int S = in_sizes[1] / D;
    const int Q = in_sizes[2] / D;
    const int N = in_sizes[3] / D;
    const int NSLICE = N / 64;   // 256
    const int FBLK = Q / 4;

    char* p = (char*)d_ws;
    unsigned short* queb = (unsigned short*)p; p += (size_t)Q * D * 2;
    unsigned short* senb = (unsigned short*)p; p += (size_t)N * D * 2;
    unsigned short* secb = (unsigned short*)p; p += (size_t)S * D * 2;
    float* simq = (float*)p; p += (size_t)Q * 4;
    float* pos_s = (float*)p; p += (size_t)Q * CAP * 4;
    float* partial = (float*)p; p += (size_t)NSLICE * Q * 4;
    float* bpart = (float*)p; p += (size_t)FBLK * 4 * 4;
    char* z0 = p;
    int* cnt = (int*)p; p += (size_t)Q * 4;
    float* sq_all = (float*)p; p += (size_t)S * 4;
    float* sq_pos = (float*)p; p += (size_t)S * 4;
    int* sq_m = (int*)p; p += (size_t)S * 4;
    size_t zbytes = (size_t)(p - z0);

    hipMemsetAsync(z0, 0, zbytes, stream);
    norm_all<<<(Q + N + S + 3) / 4, 256, 0, stream>>>(que, sen, sec, queb, senb, secb, Q, N, S);
    // 32 SQ blocks + 4096 QS blocks (each = 4 independent 64x64 wave-tiles).
    qs_sq<<<Q / 128 + (Q / 128) * (N / 128), 256, 0, stream>>>(queb, senb, secb, pidq, pidn,
                                                               sidx, Q, partial, cnt, pos_s,
                                                               sq_all, sq_pos, sq_m, simq);
    finish<<<FBLK, 256, 0, stream>>>(partial, NSLICE, cnt, pos_s, sidx, simq,
                                     sq_all, sq_pos, sq_m, npp, Q, N, bpart);
    combine2<<<1, 256, 0, stream>>>(bpart, FBLK, (float*)d_out);
}

// Round 15
// 90.761 us; speedup vs baseline: 1.4610x; 1.1964x over previous
//
#include <hip/hip_runtime.h>
#include <hip/hip_bf16.h>
#include <math.h>

#define D 256
#define INV_TAU 20.0f
#define CAP 64
#define PBUF 128
// fp8 inputs scaled by 16: acc = 256*sim. s = acc*INV_TAU/256.
#define ACC2S (INV_TAU / 256.0f)
#define K2F (ACC2S * 1.4426950408889634f)

typedef __attribute__((ext_vector_type(4))) float f32x4;

#define GLOAD16(gp, lp) \
    __builtin_amdgcn_global_load_lds((const __attribute__((address_space(1))) void*)(gp), \
                                     (__attribute__((address_space(3))) void*)(lp), 16, 0, 0)

// Wave per row: L2-normalize a 256-dim f32 row, scale by 16, emit fp8 e4m3.
__global__ void norm_all(const float* __restrict__ que, const float* __restrict__ sen,
                         const float* __restrict__ sec,
                         unsigned char* __restrict__ queb, unsigned char* __restrict__ senb,
                         unsigned char* __restrict__ secb, int Q, int N, int S) {
    int r = blockIdx.x * 4 + (threadIdx.x >> 6);
    int lane = threadIdx.x & 63;
    if (r >= Q + N + S) return;
    const float* src; unsigned char* dst; int row;
    if (r < Q) { src = que; dst = queb; row = r; }
    else if (r < Q + N) { src = sen; dst = senb; row = r - Q; }
    else { src = sec; dst = secb; row = r - Q - N; }
    const float4* p = (const float4*)(src + (size_t)row * D);
    float4 v = p[lane];
    float ss = v.x * v.x + v.y * v.y + v.z * v.z + v.w * v.w;
    #pragma unroll
    for (int m = 1; m < 64; m <<= 1) ss += __shfl_xor(ss, m);
    float s = rsqrtf(ss) * 16.0f;
    int pk = __builtin_amdgcn_cvt_pk_fp8_f32(v.x * s, v.y * s, 0, false);
    pk = __builtin_amdgcn_cvt_pk_fp8_f32(v.z * s, v.w * s, pk, true);
    *(int*)(dst + (size_t)row * D + lane * 4) = pk;
}

// Mega kernel, 1-D grid = 32 SQ blocks + 4096 QS blocks, 256 threads.
// QS: m97-shape GEMM in fp8 — 128x128 tile, BK=64 (64B rows), single LDS buffer,
// plain __syncthreads. LDS ~19.5KB -> 8 blocks/CU (32 waves/CU, 2x every prior
// round's residency). Chunk swizzle c ^= (row>>1)&3 on SOURCE + READ, LDS linear.
// Fragments via b64 reads (8B/lane; bank floor = free per 4-lanes/bank analysis).
__global__ __launch_bounds__(256, 4)
void qs_sq(const unsigned char* __restrict__ queb, const unsigned char* __restrict__ senb,
           const unsigned char* __restrict__ secb,
           const int* __restrict__ pidq, const int* __restrict__ pidn,
           const int* __restrict__ sidx, int Q,
           float* __restrict__ partial, int* __restrict__ cnt, float* __restrict__ pos_s,
           float* __restrict__ sq_all, float* __restrict__ sq_pos, int* __restrict__ sq_m,
           float* __restrict__ simq) {
    __shared__ unsigned char As[128 * 64];
    __shared__ unsigned char Bs[128 * 64];
    __shared__ int pqs[128];
    __shared__ int pns[128];
    __shared__ float sums[2][128];
    __shared__ int lcnt;
    __shared__ int lq[PBUF];
    __shared__ float lsv[PBUF];

    const int tid = threadIdx.x;
    const int lane = tid & 63;
    const int cl = lane & 15;
    const int g = lane >> 4;
    const int wid = tid >> 6;
    const int bid = blockIdx.x;
    const int nsq = Q >> 7;   // 32 SQ blocks

    if (bid < nsq) {
        // ---------------- SQ path: 64 sections x 128 questions (fp8) ----------------
        const int q0 = bid * 128;
        const int qw = q0 + wid * 32;
        f32x4 acc[4][2];
        #pragma unroll
        for (int si = 0; si < 4; ++si)
            #pragma unroll
            for (int qi = 0; qi < 2; ++qi)
                acc[si][qi] = (f32x4){0.f, 0.f, 0.f, 0.f};
        const unsigned char* abase = secb + (size_t)cl * D + g * 8;
        const unsigned char* bbase = queb + (size_t)(qw + cl) * D + g * 8;
        #pragma unroll
        for (int kk = 0; kk < 8; ++kk) {
            const int k0 = kk * 32;
            long af[4], bq[2];
            #pragma unroll
            for (int si = 0; si < 4; ++si)
                af[si] = *(const long*)(abase + (size_t)si * 16 * D + k0);
            #pragma unroll
            for (int qi = 0; qi < 2; ++qi)
                bq[qi] = *(const long*)(bbase + (size_t)qi * 16 * D + k0);
            #pragma unroll
            for (int si = 0; si < 4; ++si)
                #pragma unroll
                for (int qi = 0; qi < 2; ++qi)
                    acc[si][qi] = __builtin_amdgcn_mfma_f32_16x16x32_fp8_fp8(af[si], bq[qi], acc[si][qi], 0, 0, 0);
        }
        int sidxv[2];
        sidxv[0] = sidx[qw + cl];
        sidxv[1] = sidx[qw + 16 + cl];
        #pragma unroll
        for (int si = 0; si < 4; ++si) {
            float pa[4] = {0.f, 0.f, 0.f, 0.f};
            #pragma unroll
            for (int qi = 0; qi < 2; ++qi) {
                #pragma unroll
                for (int j = 0; j < 4; ++j) {
                    int srow = si * 16 + g * 4 + j;
                    float sv = acc[si][qi][j] * ACC2S;
                    float e = __expf(sv);
                    pa[j] += e;
                    if (sidxv[qi] == srow) {
                        int q = qw + qi * 16 + cl;
                        simq[q] = sv;
                        atomicAdd(&sq_pos[srow], e);
                        atomicAdd(&sq_m[srow], 1);
                    }
                }
            }
            #pragma unroll
            for (int j = 0; j < 4; ++j) {
                float a = pa[j];
                #pragma unroll
                for (int msk = 1; msk < 16; msk <<= 1) a += __shfl_xor(a, msk);
                if (cl == 0) atomicAdd(&sq_all[si * 16 + g * 4 + j], a);
            }
        }
        return;
    }

    // ---------------- QS path ----------------
    const int qbid = bid - nsq;
    const int qt = qbid & 31;       // 32 consecutive blocks share the same n-tile
    const int nt = qbid >> 5;       // 128 n-tiles
    const int wr = wid >> 1, wc = wid & 1;
    const int q0 = qt * 128;
    const int n0 = nt * 128;

    if (tid < 128) pqs[tid] = pidq[q0 + tid];
    else           pns[tid - 128] = pidn[n0 + tid - 128];
    if (tid == 0) lcnt = 0;

    // Staging: tile = 128 rows x 64 B = 512 16B-chunks per matrix; thread covers
    // cid = {tid, 256+tid}: row = cid>>2, c = cid&3. Source chunk = c ^ ((row>>1)&3),
    // LDS dest linear in cid (wave-uniform base + lane*16).
    const int r0s = tid >> 2;             // rows 0..63
    const int c0s = tid & 3;
    const unsigned char* qa0 = queb + (size_t)(q0 + r0s) * D + ((c0s ^ ((r0s >> 1) & 3)) << 4);
    const unsigned char* qa1 = queb + (size_t)(q0 + 64 + r0s) * D + ((c0s ^ (((r0s + 64) >> 1) & 3)) << 4);
    const unsigned char* sb0 = senb + (size_t)(n0 + r0s) * D + ((c0s ^ ((r0s >> 1) & 3)) << 4);
    const unsigned char* sb1 = senb + (size_t)(n0 + 64 + r0s) * D + ((c0s ^ (((r0s + 64) >> 1) & 3)) << 4);
    const int ld0 = wid * 1024;           // byte base, chunks 0..255
    const int ld1 = 4096 + wid * 1024;    // chunks 256..511

#define STAGE(k0) do { \
    GLOAD16(qa0 + (k0), &As[ld0]); \
    GLOAD16(qa1 + (k0), &As[ld1]); \
    GLOAD16(sb0 + (k0), &Bs[ld0]); \
    GLOAD16(sb1 + (k0), &Bs[ld1]); \
} while (0)

    f32x4 acc[4][4];
    #pragma unroll
    for (int m = 0; m < 4; ++m)
        #pragma unroll
        for (int n = 0; n < 4; ++n)
            acc[m][n] = (f32x4){0.f, 0.f, 0.f, 0.f};

    // Fragment byte offsets (kk=0): want global chunk (r, g>>1) half (g&1);
    // stored chunk = (g>>1) ^ ((r>>1)&3), (r>>1)&3 == (cl>>1)&3 for all frags.
    // kk=1 adds chunk +2 == XOR 2 (chunk<2 sets) -> byte XOR 32.
    const int fsw = ((((g >> 1) ^ ((cl >> 1) & 3)) << 4) | ((g & 1) << 3));
    int offA0[4], offB0[4];
    #pragma unroll
    for (int m = 0; m < 4; ++m) offA0[m] = (wr * 64 + m * 16 + cl) * 64 + fsw;
    #pragma unroll
    for (int n = 0; n < 4; ++n) offB0[n] = (wc * 64 + n * 16 + cl) * 64 + fsw;

    STAGE(0);
    #pragma unroll
    for (int ks = 0; ks < 4; ++ks) {
        __syncthreads();   // drains own vmcnt + rendezvous: LDS tile ready
        #pragma unroll
        for (int kk = 0; kk < 2; ++kk) {
            const int kx = kk << 5;
            long af[4], bg[4];
            #pragma unroll
            for (int m = 0; m < 4; ++m) af[m] = *(const long*)&As[offA0[m] ^ kx];
            #pragma unroll
            for (int n = 0; n < 4; ++n) bg[n] = *(const long*)&Bs[offB0[n] ^ kx];
            #pragma unroll
            for (int m = 0; m < 4; ++m)
                #pragma unroll
                for (int n = 0; n < 4; ++n)
                    acc[m][n] = __builtin_amdgcn_mfma_f32_16x16x32_fp8_fp8(af[m], bg[n], acc[m][n], 0, 0, 0);
        }
        if (ks < 3) {
            __syncthreads();          // all reads done before overwrite
            STAGE((ks + 1) * 64);
        }
    }
#undef STAGE

    // Epilogue: exp2 + per-row sums (block-local) + LDS positive capture.
    #pragma unroll
    for (int m = 0; m < 4; ++m) {
        float se[4] = {0.f, 0.f, 0.f, 0.f};
        int pqr[4];
        #pragma unroll
        for (int j = 0; j < 4; ++j) pqr[j] = pqs[wr * 64 + m * 16 + g * 4 + j];
        #pragma unroll
        for (int n = 0; n < 4; ++n) {
            const int pcol = pns[wc * 64 + n * 16 + cl];
            #pragma unroll
            for (int j = 0; j < 4; ++j) {
                float e = __builtin_amdgcn_exp2f(acc[m][n][j] * K2F);
                se[j] += e;
                if (pqr[j] == pcol) {
                    int li = atomicAdd(&lcnt, 1);
                    if (li < PBUF) {
                        lq[li] = q0 + wr * 64 + m * 16 + g * 4 + j;
                        lsv[li] = acc[m][n][j] * ACC2S;
                    }
                }
            }
        }
        #pragma unroll
        for (int j = 0; j < 4; ++j) {
            float a = se[j];
            #pragma unroll
            for (int msk = 1; msk < 16; msk <<= 1) a += __shfl_xor(a, msk);
            if (cl == 0) sums[wc][wr * 64 + m * 16 + g * 4 + j] = a;
        }
    }
    __syncthreads();
    if (tid < 128)
        partial[(size_t)nt * Q + q0 + tid] = sums[0][tid] + sums[1][tid];
    int nc = lcnt < PBUF ? lcnt : PBUF;
    for (int i = tid; i < nc; i += 256) {
        int q = lq[i];
        int idx = atomicAdd(&cnt[q], 1);
        if (idx < CAP) pos_s[(size_t)q * CAP + idx] = lsv[i];
    }
}

// Finish: wave per question. Reduces row partials, computes g + QS terms + SQ term.
__global__ __launch_bounds__(256)
void finish(const float* __restrict__ partial, int NSLICE,
            const int* __restrict__ cnt, const float* __restrict__ pos_s,
            const int* __restrict__ sidx, const float* __restrict__ simq,
            const float* __restrict__ sq_all, const float* __restrict__ sq_pos,
            const int* __restrict__ sq_m,
            const int* __restrict__ npp, int Qn, int Ntot,
            float* __restrict__ bpart) {
    __shared__ float fred[4][4];
    const int tid = threadIdx.x, lane = tid & 63, wid = tid >> 6;
    const int q = blockIdx.x * 4 + wid;

    float Sa = 0.f;
    for (int nb = lane; nb < NSLICE; nb += 64) Sa += partial[(size_t)nb * Qn + q];
    #pragma unroll
    for (int m = 1; m < 64; m <<= 1) Sa += __shfl_xor(Sa, m);

    int M = cnt[q];
    int mc = M < CAP ? M : CAP;
    float s = 0.f, e = 0.f;
    if (lane < mc) { s = pos_s[(size_t)q * CAP + lane]; e = __expf(s); }
    float Sp = e;
    #pragma unroll
    for (int m = 1; m < 64; m <<= 1) Sp += __shfl_xor(Sp, m);

    int Nn = Ntot - M;
    int P = npp[0];
    float eta_p = 1.0f / (float)(P > 1 ? P : 1);
    float eta_m = 1.0f - eta_p;
    float Mf = (float)(M > 1 ? M : 1);
    float Nnf = (float)(Nn > 1 ? Nn : 1);
    float gg = fmaxf(((Sa - Sp) / Nnf - eta_p * Sp / Mf) / eta_m, __expf(-INV_TAU));
    float c = (float)Nn * gg;

    float contrib = (lane < mc) ? (s - __logf(e + c)) : 0.f;
    #pragma unroll
    for (int m = 1; m < 64; m <<= 1) contrib += __shfl_xor(contrib, m);

    if (lane == 0) {
        float qs_num = 0.f, qs_cnt = 0.f, sq_num = 0.f, sq_cnt = 0.f;
        if (M > 0 && Nn > 0) { qs_num = contrib; qs_cnt = (float)M; }
        int sct = sidx[q];
        int Mq = sq_m[sct];
        if (Mq > 0 && (Qn - Mq) > 0) {
            float sv = simq[q];
            float sumneg = sq_all[sct] - sq_pos[sct];
            sq_num = sv - __logf(__expf(sv) + sumneg);
            sq_cnt = 1.f;
        }
        fred[wid][0] = qs_num; fred[wid][1] = qs_cnt;
        fred[wid][2] = sq_num; fred[wid][3] = sq_cnt;
    }
    __syncthreads();
    if (tid < 4) {
        float v = fred[0][tid] + fred[1][tid] + fred[2][tid] + fred[3][tid];
        bpart[(size_t)blockIdx.x * 4 + tid] = v;
    }
}

__global__ void combine2(const float* __restrict__ bpart, int nblk, float* __restrict__ out) {
    __shared__ float r2[4][4];
    const int tid = threadIdx.x, lane = tid & 63, wid = tid >> 6;
    float v[4] = {0.f, 0.f, 0.f, 0.f};
    for (int i = tid; i < nblk; i += 256) {
        #pragma unroll
        for (int c2 = 0; c2 < 4; ++c2) v[c2] += bpart[(size_t)i * 4 + c2];
    }
    #pragma unroll
    for (int m = 1; m < 64; m <<= 1)
        #pragma unroll
        for (int c2 = 0; c2 < 4; ++c2) v[c2] += __shfl_xor(v[c2], m);
    if (lane == 0) {
        #pragma unroll
        for (int c2 = 0; c2 < 4; ++c2) r2[wid][c2] = v[c2];
    }
    __syncthreads();
    if (tid == 0) {
        float qs_num = r2[0][0] + r2[1][0] + r2[2][0] + r2[3][0];
        float qs_cnt = r2[0][1] + r2[1][1] + r2[2][1] + r2[3][1];
        float sq_num = r2[0][2] + r2[1][2] + r2[2][2] + r2[3][2];
        float sq_cnt = r2[0][3] + r2[1][3] + r2[2][3] + r2[3][3];
        float qs = qs_cnt > 0.f ? -qs_num / qs_cnt : 0.f;
        float sq = sq_cnt > 0.f ? -sq_num / sq_cnt : 0.f;
        out[0] = qs + sq;
    }
}

extern "C" void kernel_launch(void* const* d_in, const int* in_sizes, int n_in,
                              void* d_out, int out_size, void* d_ws, size_t ws_size,
                              hipStream_t stream) {
    const float* sec = (const float*)d_in[1];
    const float* que = (const float*)d_in[2];
    const float* sen = (const float*)d_in[3];
    const int* pidq = (const int*)d_in[4];
    const int* sidx = (const int*)d_in[5];
    const int* pidn = (const int*)d_in[6];
    const int* npp = (const int*)d_in[7];
    const int S = in_sizes[1] / D;
    const int Q = in_sizes[2] / D;
    const int N = in_sizes[3] / D;
    const int NB = N / 128;
    const int FBLK = Q / 4;

    char* p = (char*)d_ws;
    unsigned char* queb = (unsigned char*)p; p += (size_t)Q * D;
    unsigned char* senb = (unsigned char*)p; p += (size_t)N * D;
    unsigned char* secb = (unsigned char*)p; p += (size_t)S * D;
    p = (char*)(((uintptr_t)p + 255) & ~(uintptr_t)255);
    float* simq = (float*)p; p += (size_t)Q * 4;
    float* pos_s = (float*)p; p += (size_t)Q * CAP * 4;
    float* partial = (float*)p; p += (size_t)NB * Q * 4;
    float* bpart = (float*)p; p += (size_t)FBLK * 4 * 4;
    char* z0 = p;
    int* cnt = (int*)p; p += (size_t)Q * 4;
    float* sq_all = (float*)p; p += (size_t)S * 4;
    float* sq_pos = (float*)p; p += (size_t)S * 4;
    int* sq_m = (int*)p; p += (size_t)S * 4;
    size_t zbytes = (size_t)(p - z0);

    hipMemsetAsync(z0, 0, zbytes, stream);
    norm_all<<<(Q + N + S + 3) / 4, 256, 0, stream>>>(que, sen, sec, queb, senb, secb, Q, N, S);
    qs_sq<<<Q / 128 + (Q / 128) * NB, 256, 0, stream>>>(queb, senb, secb, pidq, pidn, sidx, Q,
                                                        partial, cnt, pos_s,
                                                        sq_all, sq_pos, sq_m, simq);
    finish<<<FBLK, 256, 0, stream>>>(partial, NB, cnt, pos_s, sidx, simq,
                                     sq_all, sq_pos, sq_m, npp, Q, N, bpart);
    combine2<<<1, 256, 0, stream>>>(bpart, FBLK, (float*)d_out);
}

// Round 16
// 86.279 us; speedup vs baseline: 1.5369x; 1.0520x over previous
//
#include <hip/hip_runtime.h>
#include <hip/hip_bf16.h>
#include <math.h>

#define D 256
#define INV_TAU 20.0f
#define CAP 64
#define PBUF 128
// fp8 inputs scaled by 16: acc = 256*sim. s = acc*INV_TAU/256.
#define ACC2S (INV_TAU / 256.0f)
#define K2F (ACC2S * 1.4426950408889634f)

typedef __attribute__((ext_vector_type(4))) float f32x4;

#define GLOAD16(gp, lp) \
    __builtin_amdgcn_global_load_lds((const __attribute__((address_space(1))) void*)(gp), \
                                     (__attribute__((address_space(3))) void*)(lp), 16, 0, 0)

// Wave per row: L2-normalize a 256-dim f32 row, scale by 16, emit fp8 e4m3 in
// PERMUTED layout: each 64B K-block stores granules (8B) in order [0,4,1,5,2,6,3,7],
// so positions (2g,2g+1) hold the MFMA operands of kk-pair (even,odd) for lane g —
// one ds_read_b128 serves two K-steps with R6's verified 0-conflict geometry.
__global__ void norm_all(const float* __restrict__ que, const float* __restrict__ sen,
                         const float* __restrict__ sec,
                         unsigned char* __restrict__ queb, unsigned char* __restrict__ senb,
                         unsigned char* __restrict__ secb, int Q, int N, int S) {
    int r = blockIdx.x * 4 + (threadIdx.x >> 6);
    int lane = threadIdx.x & 63;
    if (r >= Q + N + S) return;
    const float* src; unsigned char* dst; int row;
    if (r < Q) { src = que; dst = queb; row = r; }
    else if (r < Q + N) { src = sen; dst = senb; row = r - Q; }
    else { src = sec; dst = secb; row = r - Q - N; }
    const float4* p = (const float4*)(src + (size_t)row * D);
    float4 v = p[lane];
    float ss = v.x * v.x + v.y * v.y + v.z * v.z + v.w * v.w;
    #pragma unroll
    for (int m = 1; m < 64; m <<= 1) ss += __shfl_xor(ss, m);
    float s = rsqrtf(ss) * 16.0f;
    int pk = __builtin_amdgcn_cvt_pk_fp8_f32(v.x * s, v.y * s, 0, false);
    pk = __builtin_amdgcn_cvt_pk_fp8_f32(v.z * s, v.w * s, pk, true);
    // lane covers granule (lane>>1), half (lane&1); block = lane>>4, wg = (lane>>1)&7.
    int wg = (lane >> 1) & 7;
    int pos = (wg < 4) ? (2 * wg) : (2 * (wg - 4) + 1);
    int byte = ((lane >> 4) << 6) + (pos << 3) + ((lane & 1) << 2);
    *(int*)(dst + (size_t)row * D + byte) = pk;
}

// Mega kernel, 1-D grid = 32 SQ blocks + 4096 QS blocks, 256 threads.
// QS: m97-shape fp8 GEMM — 128x128 tile, BK=64 (one permuted 64B block/step),
// single LDS buffer, plain __syncthreads. Chunk swizzle c ^= (row>>1)&3 on
// SOURCE + READ, LDS linear (rule #21). Fragment = ONE ds_read_b128 per (r, two
// kk-steps): byte = r*64 + (g^((r>>1)&3))*16 — R6's measured-0-conflict pattern.
__global__ __launch_bounds__(256, 4)
void qs_sq(const unsigned char* __restrict__ queb, const unsigned char* __restrict__ senb,
           const unsigned char* __restrict__ secb,
           const int* __restrict__ pidq, const int* __restrict__ pidn,
           const int* __restrict__ sidx, int Q,
           float* __restrict__ partial, int* __restrict__ cnt, float* __restrict__ pos_s,
           float* __restrict__ sq_all, float* __restrict__ sq_pos, int* __restrict__ sq_m,
           float* __restrict__ simq) {
    __shared__ unsigned char As[128 * 64];
    __shared__ unsigned char Bs[128 * 64];
    __shared__ int pqs[128];
    __shared__ int pns[128];
    __shared__ float sums[2][128];
    __shared__ int lcnt;
    __shared__ int lq[PBUF];
    __shared__ float lsv[PBUF];

    const int tid = threadIdx.x;
    const int lane = tid & 63;
    const int cl = lane & 15;
    const int g = lane >> 4;
    const int wid = tid >> 6;
    const int bid = blockIdx.x;
    const int nsq = Q >> 7;   // 32 SQ blocks

    if (bid < nsq) {
        // ---------------- SQ path: 64 sections x 128 questions (fp8, permuted) ----------------
        const int q0 = bid * 128;
        const int qw = q0 + wid * 32;
        f32x4 acc[4][2];
        #pragma unroll
        for (int si = 0; si < 4; ++si)
            #pragma unroll
            for (int qi = 0; qi < 2; ++qi)
                acc[si][qi] = (f32x4){0.f, 0.f, 0.f, 0.f};
        const unsigned char* abase = secb + (size_t)cl * D + g * 16;
        const unsigned char* bbase = queb + (size_t)(qw + cl) * D + g * 16;
        #pragma unroll
        for (int b = 0; b < 4; ++b) {
            const int k0 = b * 64;
            long2 af[4], bq[2];
            #pragma unroll
            for (int si = 0; si < 4; ++si)
                af[si] = *(const long2*)(abase + (size_t)si * 16 * D + k0);
            #pragma unroll
            for (int qi = 0; qi < 2; ++qi)
                bq[qi] = *(const long2*)(bbase + (size_t)qi * 16 * D + k0);
            #pragma unroll
            for (int si = 0; si < 4; ++si)
                #pragma unroll
                for (int qi = 0; qi < 2; ++qi) {
                    acc[si][qi] = __builtin_amdgcn_mfma_f32_16x16x32_fp8_fp8(af[si].x, bq[qi].x, acc[si][qi], 0, 0, 0);
                    acc[si][qi] = __builtin_amdgcn_mfma_f32_16x16x32_fp8_fp8(af[si].y, bq[qi].y, acc[si][qi], 0, 0, 0);
                }
        }
        int sidxv[2];
        sidxv[0] = sidx[qw + cl];
        sidxv[1] = sidx[qw + 16 + cl];
        #pragma unroll
        for (int si = 0; si < 4; ++si) {
            float pa[4] = {0.f, 0.f, 0.f, 0.f};
            #pragma unroll
            for (int qi = 0; qi < 2; ++qi) {
                #pragma unroll
                for (int j = 0; j < 4; ++j) {
                    int srow = si * 16 + g * 4 + j;
                    float sv = acc[si][qi][j] * ACC2S;
                    float e = __expf(sv);
                    pa[j] += e;
                    if (sidxv[qi] == srow) {
                        int q = qw + qi * 16 + cl;
                        simq[q] = sv;
                        atomicAdd(&sq_pos[srow], e);
                        atomicAdd(&sq_m[srow], 1);
                    }
                }
            }
            #pragma unroll
            for (int j = 0; j < 4; ++j) {
                float a = pa[j];
                #pragma unroll
                for (int msk = 1; msk < 16; msk <<= 1) a += __shfl_xor(a, msk);
                if (cl == 0) atomicAdd(&sq_all[si * 16 + g * 4 + j], a);
            }
        }
        return;
    }

    // ---------------- QS path ----------------
    const int qbid = bid - nsq;
    const int qt = qbid & 31;       // 32 consecutive blocks share the same n-tile
    const int nt = qbid >> 5;       // 128 n-tiles
    const int wr = wid >> 1, wc = wid & 1;
    const int q0 = qt * 128;
    const int n0 = nt * 128;

    if (tid < 128) pqs[tid] = pidq[q0 + tid];
    else           pns[tid - 128] = pidn[n0 + tid - 128];
    if (tid == 0) lcnt = 0;

    // Staging: per K-step stage one 64B block: 128 rows x 4 chunks = 512 chunks
    // per matrix; thread covers cid = {tid, 256+tid}: row = cid>>2, c = cid&3.
    // Source chunk = c ^ ((row>>1)&3), LDS dest linear in cid.
    const int r0s = tid >> 2;             // rows 0..63
    const int c0s = tid & 3;
    const unsigned char* qa0 = queb + (size_t)(q0 + r0s) * D + ((c0s ^ ((r0s >> 1) & 3)) << 4);
    const unsigned char* qa1 = queb + (size_t)(q0 + 64 + r0s) * D + ((c0s ^ (((r0s + 64) >> 1) & 3)) << 4);
    const unsigned char* sb0 = senb + (size_t)(n0 + r0s) * D + ((c0s ^ ((r0s >> 1) & 3)) << 4);
    const unsigned char* sb1 = senb + (size_t)(n0 + 64 + r0s) * D + ((c0s ^ (((r0s + 64) >> 1) & 3)) << 4);
    const int ld0 = wid * 1024;           // byte base, chunks 0..255
    const int ld1 = 4096 + wid * 1024;    // chunks 256..511

#define STAGE(k0) do { \
    GLOAD16(qa0 + (k0), &As[ld0]); \
    GLOAD16(qa1 + (k0), &As[ld1]); \
    GLOAD16(sb0 + (k0), &Bs[ld0]); \
    GLOAD16(sb1 + (k0), &Bs[ld1]); \
} while (0)

    f32x4 acc[4][4];
    #pragma unroll
    for (int m = 0; m < 4; ++m)
        #pragma unroll
        for (int n = 0; n < 4; ++n)
            acc[m][n] = (f32x4){0.f, 0.f, 0.f, 0.f};

    // Fragment byte offsets: want global chunk (r, g); stored chunk = g ^ ((r>>1)&3),
    // and (r>>1)&3 == (cl>>1)&3 for all fragment rows (bases are multiples of 16).
    // One b128 per (frag row): lo 8B = kk-even operand, hi 8B = kk-odd operand.
    const int fsw = (g ^ ((cl >> 1) & 3)) << 4;
    int offA[4], offB[4];
    #pragma unroll
    for (int m = 0; m < 4; ++m) offA[m] = (wr * 64 + m * 16 + cl) * 64 + fsw;
    #pragma unroll
    for (int n = 0; n < 4; ++n) offB[n] = (wc * 64 + n * 16 + cl) * 64 + fsw;

    STAGE(0);
    #pragma unroll
    for (int ks = 0; ks < 4; ++ks) {
        __syncthreads();   // drains own vmcnt + rendezvous: LDS tile ready
        long2 af[4], bg[4];
        #pragma unroll
        for (int m = 0; m < 4; ++m) af[m] = *(const long2*)&As[offA[m]];
        #pragma unroll
        for (int n = 0; n < 4; ++n) bg[n] = *(const long2*)&Bs[offB[n]];
        #pragma unroll
        for (int m = 0; m < 4; ++m)
            #pragma unroll
            for (int n = 0; n < 4; ++n)
                acc[m][n] = __builtin_amdgcn_mfma_f32_16x16x32_fp8_fp8(af[m].x, bg[n].x, acc[m][n], 0, 0, 0);
        #pragma unroll
        for (int m = 0; m < 4; ++m)
            #pragma unroll
            for (int n = 0; n < 4; ++n)
                acc[m][n] = __builtin_amdgcn_mfma_f32_16x16x32_fp8_fp8(af[m].y, bg[n].y, acc[m][n], 0, 0, 0);
        if (ks < 3) {
            __syncthreads();          // all reads done before overwrite
            STAGE((ks + 1) * 64);
        }
    }
#undef STAGE

    // Epilogue: exp2 + per-row sums (block-local) + LDS positive capture.
    #pragma unroll
    for (int m = 0; m < 4; ++m) {
        float se[4] = {0.f, 0.f, 0.f, 0.f};
        int pqr[4];
        #pragma unroll
        for (int j = 0; j < 4; ++j) pqr[j] = pqs[wr * 64 + m * 16 + g * 4 + j];
        #pragma unroll
        for (int n = 0; n < 4; ++n) {
            const int pcol = pns[wc * 64 + n * 16 + cl];
            #pragma unroll
            for (int j = 0; j < 4; ++j) {
                float e = __builtin_amdgcn_exp2f(acc[m][n][j] * K2F);
                se[j] += e;
                if (pqr[j] == pcol) {
                    int li = atomicAdd(&lcnt, 1);
                    if (li < PBUF) {
                        lq[li] = q0 + wr * 64 + m * 16 + g * 4 + j;
                        lsv[li] = acc[m][n][j] * ACC2S;
                    }
                }
            }
        }
        #pragma unroll
        for (int j = 0; j < 4; ++j) {
            float a = se[j];
            #pragma unroll
            for (int msk = 1; msk < 16; msk <<= 1) a += __shfl_xor(a, msk);
            if (cl == 0) sums[wc][wr * 64 + m * 16 + g * 4 + j] = a;
        }
    }
    __syncthreads();
    if (tid < 128)
        partial[(size_t)nt * Q + q0 + tid] = sums[0][tid] + sums[1][tid];
    int nc = lcnt < PBUF ? lcnt : PBUF;
    for (int i = tid; i < nc; i += 256) {
        int q = lq[i];
        int idx = atomicAdd(&cnt[q], 1);
        if (idx < CAP) pos_s[(size_t)q * CAP + idx] = lsv[i];
    }
}

// Finish: wave per question. Reduces row partials, computes g + QS terms + SQ term.
__global__ __launch_bounds__(256)
void finish(const float* __restrict__ partial, int NSLICE,
            const int* __restrict__ cnt, const float* __restrict__ pos_s,
            const int* __restrict__ sidx, const float* __restrict__ simq,
            const float* __restrict__ sq_all, const float* __restrict__ sq_pos,
            const int* __restrict__ sq_m,
            const int* __restrict__ npp, int Qn, int Ntot,
            float* __restrict__ bpart) {
    __shared__ float fred[4][4];
    const int tid = threadIdx.x, lane = tid & 63, wid = tid >> 6;
    const int q = blockIdx.x * 4 + wid;

    float Sa = 0.f;
    for (int nb = lane; nb < NSLICE; nb += 64) Sa += partial[(size_t)nb * Qn + q];
    #pragma unroll
    for (int m = 1; m < 64; m <<= 1) Sa += __shfl_xor(Sa, m);

    int M = cnt[q];
    int mc = M < CAP ? M : CAP;
    float s = 0.f, e = 0.f;
    if (lane < mc) { s = pos_s[(size_t)q * CAP + lane]; e = __expf(s); }
    float Sp = e;
    #pragma unroll
    for (int m = 1; m < 64; m <<= 1) Sp += __shfl_xor(Sp, m);

    int Nn = Ntot - M;
    int P = npp[0];
    float eta_p = 1.0f / (float)(P > 1 ? P : 1);
    float eta_m = 1.0f - eta_p;
    float Mf = (float)(M > 1 ? M : 1);
    float Nnf = (float)(Nn > 1 ? Nn : 1);
    float gg = fmaxf(((Sa - Sp) / Nnf - eta_p * Sp / Mf) / eta_m, __expf(-INV_TAU));
    float c = (float)Nn * gg;

    float contrib = (lane < mc) ? (s - __logf(e + c)) : 0.f;
    #pragma unroll
    for (int m = 1; m < 64; m <<= 1) contrib += __shfl_xor(contrib, m);

    if (lane == 0) {
        float qs_num = 0.f, qs_cnt = 0.f, sq_num = 0.f, sq_cnt = 0.f;
        if (M > 0 && Nn > 0) { qs_num = contrib; qs_cnt = (float)M; }
        int sct = sidx[q];
        int Mq = sq_m[sct];
        if (Mq > 0 && (Qn - Mq) > 0) {
            float sv = simq[q];
            float sumneg = sq_all[sct] - sq_pos[sct];
            sq_num = sv - __logf(__expf(sv) + sumneg);
            sq_cnt = 1.f;
        }
        fred[wid][0] = qs_num; fred[wid][1] = qs_cnt;
        fred[wid][2] = sq_num; fred[wid][3] = sq_cnt;
    }
    __syncthreads();
    if (tid < 4) {
        float v = fred[0][tid] + fred[1][tid] + fred[2][tid] + fred[3][tid];
        bpart[(size_t)blockIdx.x * 4 + tid] = v;
    }
}

__global__ void combine2(const float* __restrict__ bpart, int nblk, float* __restrict__ out) {
    __shared__ float r2[4][4];
    const int tid = threadIdx.x, lane = tid & 63, wid = tid >> 6;
    float v[4] = {0.f, 0.f, 0.f, 0.f};
    for (int i = tid; i < nblk; i += 256) {
        #pragma unroll
        for (int c2 = 0; c2 < 4; ++c2) v[c2] += bpart[(size_t)i * 4 + c2];
    }
    #pragma unroll
    for (int m = 1; m < 64; m <<= 1)
        #pragma unroll
        for (int c2 = 0; c2 < 4; ++c2) v[c2] += __shfl_xor(v[c2], m);
    if (lane == 0) {
        #pragma unroll
        for (int c2 = 0; c2 < 4; ++c2) r2[wid][c2] = v[c2];
    }
    __syncthreads();
    if (tid == 0) {
        float qs_num = r2[0][0] + r2[1][0] + r2[2][0] + r2[3][0];
        float qs_cnt = r2[0][1] + r2[1][1] + r2[2][1] + r2[3][1];
        float sq_num = r2[0][2] + r2[1][2] + r2[2][2] + r2[3][2];
        float sq_cnt = r2[0][3] + r2[1][3] + r2[2][3] + r2[3][3];
        float qs = qs_cnt > 0.f ? -qs_num / qs_cnt : 0.f;
        float sq = sq_cnt > 0.f ? -sq_num / sq_cnt : 0.f;
        out[0] = qs + sq;
    }
}

extern "C" void kernel_launch(void* const* d_in, const int* in_sizes, int n_in,
                              void* d_out, int out_size, void* d_ws, size_t ws_size,
                              hipStream_t stream) {
    const float* sec = (const float*)d_in[1];
    const float* que = (const float*)d_in[2];
    const float* sen = (const float*)d_in[3];
    const int* pidq = (const int*)d_in[4];
    const int* sidx = (const int*)d_in[5];
    const int* pidn = (const int*)d_in[6];
    const int* npp = (const int*)d_in[7];
    const int S = in_sizes[1] / D;
    const int Q = in_sizes[2] / D;
    const int N = in_sizes[3] / D;
    const int NB = N / 128;
    const int FBLK = Q / 4;

    char* p = (char*)d_ws;
    unsigned char* queb = (unsigned char*)p; p += (size_t)Q * D;
    unsigned char* senb = (unsigned char*)p; p += (size_t)N * D;
    unsigned char* secb = (unsigned char*)p; p += (size_t)S * D;
    p = (char*)(((uintptr_t)p + 255) & ~(uintptr_t)255);
    float* simq = (float*)p; p += (size_t)Q * 4;
    float* pos_s = (float*)p; p += (size_t)Q * CAP * 4;
    float* partial = (float*)p; p += (size_t)NB * Q * 4;
    float* bpart = (float*)p; p += (size_t)FBLK * 4 * 4;
    char* z0 = p;
    int* cnt = (int*)p; p += (size_t)Q * 4;
    float* sq_all = (float*)p; p += (size_t)S * 4;
    float* sq_pos = (float*)p; p += (size_t)S * 4;
    int* sq_m = (int*)p; p += (size_t)S * 4;
    size_t zbytes = (size_t)(p - z0);

    hipMemsetAsync(z0, 0, zbytes, stream);
    norm_all<<<(Q + N + S + 3) / 4, 256, 0, stream>>>(que, sen, sec, queb, senb, secb, Q, N, S);
    qs_sq<<<Q / 128 + (Q / 128) * NB, 256, 0, stream>>>(queb, senb, secb, pidq, pidn, sidx, Q,
                                                        partial, cnt, pos_s,
                                                        sq_all, sq_pos, sq_m, simq);
    finish<<<FBLK, 256, 0, stream>>>(partial, NB, cnt, pos_s, sidx, simq,
                                     sq_all, sq_pos, sq_m, npp, Q, N, bpart);
    combine2<<<1, 256, 0, stream>>>(bpart, FBLK, (float*)d_out);
}